// Round 1
// baseline (9871.080 us; speedup 1.0000x reference)
//
#include <hip/hip_runtime.h>

// Problem constants (match reference)
constexpr int NN  = 50000;
constexpr int EEg = 1600000;          // edges before self-loops
constexpr int EA  = EEg + NN;         // edges after self-loops
constexpr int IND = 16;
constexpr int FD  = 20;
constexpr int H1D = 4;
constexpr int ED  = 7;
constexpr int OUTD = 3;

__device__ __forceinline__ unsigned fenc(float f) {
    unsigned u = __float_as_uint(f);
    return (u & 0x80000000u) ? ~u : (u | 0x80000000u);
}
__device__ __forceinline__ float fdec(unsigned u) {
    return __uint_as_float((u & 0x80000000u) ? (u & 0x7FFFFFFFu) : ~u);
}
__device__ __forceinline__ float lrelu(float x) { return x >= 0.0f ? x : 0.2f * x; }
__device__ __forceinline__ float elu(float x)   { return x > 0.0f ? x : expm1f(x); }

// ---- degree + edge_attr scatter-sum (for self-loop mean attr) ----
__global__ void k_deg_attr(const int* __restrict__ ei, const float* __restrict__ eattr,
                           float* __restrict__ deg, float* __restrict__ asum) {
    int e = blockIdx.x * blockDim.x + threadIdx.x;
    if (e >= EEg) return;
    int dst = ei[EEg + e];
    atomicAdd(&deg[dst], 1.0f);
#pragma unroll
    for (int j = 0; j < ED; ++j) atomicAdd(&asum[dst * ED + j], eattr[e * ED + j]);
}

// ---- tiny: ve1[d*4+h] = sum_f We1[d,h*F+f]*att_e1[h,f]; ve2[d] likewise ----
__global__ void k_ve(const float* __restrict__ We1, const float* __restrict__ ae1,
                     const float* __restrict__ We2, const float* __restrict__ ae2,
                     float* __restrict__ ve1, float* __restrict__ ve2) {
    int t = threadIdx.x;
    if (t < ED * H1D) {
        int d = t >> 2, h = t & 3;
        float s = 0.0f;
        for (int f = 0; f < FD; ++f) s += We1[d * (H1D * FD) + h * FD + f] * ae1[h * FD + f];
        ve1[t] = s;
    } else if (t < ED * H1D + ED) {
        int d = t - ED * H1D;
        float s = 0.0f;
        for (int f = 0; f < FD; ++f) s += We2[d * FD + f] * ae2[f];
        ve2[d] = s;
    }
}

// ---- per-node: mean attr -> self-loop a_edge for both layers ----
__global__ void k_mean_self(const float* __restrict__ deg, const float* __restrict__ asum,
                            const float* __restrict__ ve1, const float* __restrict__ ve2,
                            float* __restrict__ a_edge1, float* __restrict__ a_edge2) {
    int n = blockIdx.x * blockDim.x + threadIdx.x;
    if (n >= NN) return;
    float inv = 1.0f / fmaxf(deg[n], 1.0f);
    float m[ED];
#pragma unroll
    for (int d = 0; d < ED; ++d) m[d] = asum[n * ED + d] * inv;
#pragma unroll
    for (int h = 0; h < H1D; ++h) {
        float s = 0.0f;
#pragma unroll
        for (int d = 0; d < ED; ++d) s += m[d] * ve1[d * H1D + h];
        a_edge1[(size_t)(EEg + n) * H1D + h] = s;
    }
    float s2 = 0.0f;
#pragma unroll
    for (int d = 0; d < ED; ++d) s2 += m[d] * ve2[d];
    a_edge2[EEg + n] = s2;
}

// ---- per-edge a_edge for real edges ----
__global__ void k_aedge(const float* __restrict__ eattr, const float* __restrict__ ve1,
                        const float* __restrict__ ve2, float* __restrict__ a_edge1,
                        float* __restrict__ a_edge2) {
    int e = blockIdx.x * blockDim.x + threadIdx.x;
    if (e >= EEg) return;
    float a[ED];
#pragma unroll
    for (int d = 0; d < ED; ++d) a[d] = eattr[e * ED + d];
#pragma unroll
    for (int h = 0; h < H1D; ++h) {
        float s = 0.0f;
#pragma unroll
        for (int d = 0; d < ED; ++d) s += a[d] * ve1[d * H1D + h];
        a_edge1[(size_t)e * H1D + h] = s;
    }
    float s2 = 0.0f;
#pragma unroll
    for (int d = 0; d < ED; ++d) s2 += a[d] * ve2[d];
    a_edge2[e] = s2;
}

// ---- xh1 = x @ W1  ([N,16] @ [16,80]) ----
__global__ void k_xh1(const float* __restrict__ x, const float* __restrict__ W1,
                      float* __restrict__ xh1) {
    __shared__ float sW[IND * H1D * FD];
    for (int i = threadIdx.x; i < IND * H1D * FD; i += blockDim.x) sW[i] = W1[i];
    __syncthreads();
    int idx = blockIdx.x * blockDim.x + threadIdx.x;
    if (idx >= NN * H1D * FD) return;
    int n = idx / (H1D * FD), j = idx % (H1D * FD);
    const float* xr = &x[n * IND];
    float s = 0.0f;
#pragma unroll
    for (int k = 0; k < IND; ++k) s += xr[k] * sW[k * (H1D * FD) + j];
    xh1[idx] = s;
}

// ---- a_src1 / a_dst1 per (node, head) ----
__global__ void k_attn1(const float* __restrict__ xh1, const float* __restrict__ as,
                        const float* __restrict__ ad, float* __restrict__ a_src1,
                        float* __restrict__ a_dst1) {
    int idx = blockIdx.x * blockDim.x + threadIdx.x;
    if (idx >= NN * H1D) return;
    int n = idx >> 2, h = idx & 3;
    const float* xr = &xh1[(size_t)n * (H1D * FD) + h * FD];
    float ss = 0.0f, sd = 0.0f;
#pragma unroll
    for (int f = 0; f < FD; ++f) { float v = xr[f]; ss += v * as[h * FD + f]; sd += v * ad[h * FD + f]; }
    a_src1[idx] = ss; a_dst1[idx] = sd;
}

// ---- conv1 pass A: segment max over dst via uint-encoded atomicMax ----
__global__ void k_passA1(const int* __restrict__ ei, const float* __restrict__ a_src1,
                         const float* __restrict__ a_dst1, const float* __restrict__ a_edge1,
                         unsigned* __restrict__ m1) {
    int t = blockIdx.x * blockDim.x + threadIdx.x;
    if (t >= EA * H1D) return;
    int e = t >> 2, h = t & 3;
    int s, dn;
    if (e < EEg) { s = ei[e]; dn = ei[EEg + e]; } else { s = dn = e - EEg; }
    float l = lrelu(a_src1[s * H1D + h] + a_dst1[dn * H1D + h] + a_edge1[(size_t)e * H1D + h]);
    atomicMax(&m1[dn * H1D + h], fenc(l));
}

// ---- conv1 pass B: exp, denom, unnormalized message accumulation ----
__global__ void k_passB1(const int* __restrict__ ei, const float* __restrict__ a_src1,
                         const float* __restrict__ a_dst1, const float* __restrict__ a_edge1,
                         const unsigned* __restrict__ m1, const float* __restrict__ xh1,
                         float* __restrict__ denom1, float* __restrict__ acc1) {
    int t = blockIdx.x * blockDim.x + threadIdx.x;
    if (t >= EA * H1D) return;
    int e = t >> 2, h = t & 3;
    int s, dn;
    if (e < EEg) { s = ei[e]; dn = ei[EEg + e]; } else { s = dn = e - EEg; }
    float l = lrelu(a_src1[s * H1D + h] + a_dst1[dn * H1D + h] + a_edge1[(size_t)e * H1D + h]);
    float ex = expf(l - fdec(m1[dn * H1D + h]));
    atomicAdd(&denom1[dn * H1D + h], ex);
    const float* xr = &xh1[(size_t)s * (H1D * FD) + h * FD];
    float* ar = &acc1[(size_t)dn * (H1D * FD) + h * FD];
#pragma unroll
    for (int f = 0; f < FD; ++f) atomicAdd(&ar[f], ex * xr[f]);
}

// ---- conv1 normalize + bias + elu (in place -> h1) ----
__global__ void k_norm1(float* __restrict__ acc1, const float* __restrict__ denom1,
                        const float* __restrict__ b1) {
    int idx = blockIdx.x * blockDim.x + threadIdx.x;
    if (idx >= NN * H1D * FD) return;
    int n = idx / (H1D * FD), j = idx % (H1D * FD), h = j / FD;
    float v = acc1[idx] / (denom1[n * H1D + h] + 1e-16f) + b1[j];
    acc1[idx] = elu(v);
}

// ---- xh2 = h1 @ W2  ([N,80] @ [80,20]) ----
__global__ void k_xh2(const float* __restrict__ h1, const float* __restrict__ W2,
                      float* __restrict__ xh2) {
    __shared__ float sW[H1D * FD * FD];
    for (int i = threadIdx.x; i < H1D * FD * FD; i += blockDim.x) sW[i] = W2[i];
    __syncthreads();
    int idx = blockIdx.x * blockDim.x + threadIdx.x;
    if (idx >= NN * FD) return;
    int n = idx / FD, f = idx % FD;
    const float* hr = &h1[(size_t)n * (H1D * FD)];
    float s = 0.0f;
#pragma unroll
    for (int k = 0; k < H1D * FD; ++k) s += hr[k] * sW[k * FD + f];
    xh2[idx] = s;
}

// ---- a_src2 / a_dst2 per node ----
__global__ void k_attn2(const float* __restrict__ xh2, const float* __restrict__ as,
                        const float* __restrict__ ad, float* __restrict__ a_src2,
                        float* __restrict__ a_dst2) {
    int n = blockIdx.x * blockDim.x + threadIdx.x;
    if (n >= NN) return;
    const float* xr = &xh2[(size_t)n * FD];
    float ss = 0.0f, sd = 0.0f;
#pragma unroll
    for (int f = 0; f < FD; ++f) { float v = xr[f]; ss += v * as[f]; sd += v * ad[f]; }
    a_src2[n] = ss; a_dst2[n] = sd;
}

__global__ void k_passA2(const int* __restrict__ ei, const float* __restrict__ a_src2,
                         const float* __restrict__ a_dst2, const float* __restrict__ a_edge2,
                         unsigned* __restrict__ m2) {
    int e = blockIdx.x * blockDim.x + threadIdx.x;
    if (e >= EA) return;
    int s, dn;
    if (e < EEg) { s = ei[e]; dn = ei[EEg + e]; } else { s = dn = e - EEg; }
    float l = lrelu(a_src2[s] + a_dst2[dn] + a_edge2[e]);
    atomicMax(&m2[dn], fenc(l));
}

__global__ void k_passB2(const int* __restrict__ ei, const float* __restrict__ a_src2,
                         const float* __restrict__ a_dst2, const float* __restrict__ a_edge2,
                         const unsigned* __restrict__ m2, const float* __restrict__ xh2,
                         float* __restrict__ denom2, float* __restrict__ acc2) {
    int e = blockIdx.x * blockDim.x + threadIdx.x;
    if (e >= EA) return;
    int s, dn;
    if (e < EEg) { s = ei[e]; dn = ei[EEg + e]; } else { s = dn = e - EEg; }
    float l = lrelu(a_src2[s] + a_dst2[dn] + a_edge2[e]);
    float ex = expf(l - fdec(m2[dn]));
    atomicAdd(&denom2[dn], ex);
    const float* xr = &xh2[(size_t)s * FD];
    float* ar = &acc2[(size_t)dn * FD];
#pragma unroll
    for (int f = 0; f < FD; ++f) atomicAdd(&ar[f], ex * xr[f]);
}

// ---- conv2 normalize + elu + decoder MLP ----
__global__ void k_final(const float* __restrict__ acc2, const float* __restrict__ denom2,
                        const float* __restrict__ b2, const float* __restrict__ D1w,
                        const float* __restrict__ D1b, const float* __restrict__ D2w,
                        const float* __restrict__ D2b, float* __restrict__ out) {
    int n = blockIdx.x * blockDim.x + threadIdx.x;
    if (n >= NN) return;
    float inv = 1.0f / (denom2[n] + 1e-16f);
    float h2[FD];
#pragma unroll
    for (int f = 0; f < FD; ++f) h2[f] = elu(acc2[(size_t)n * FD + f] * inv + b2[f]);
    float o[OUTD];
#pragma unroll
    for (int k = 0; k < OUTD; ++k) o[k] = D2b[k];
    for (int j = 0; j < 10; ++j) {
        float hid = D1b[j];
#pragma unroll
        for (int f = 0; f < FD; ++f) hid += h2[f] * D1w[f * 10 + j];
        hid = fmaxf(hid, 0.0f);
#pragma unroll
        for (int k = 0; k < OUTD; ++k) o[k] += hid * D2w[j * OUTD + k];
    }
#pragma unroll
    for (int k = 0; k < OUTD; ++k) out[n * OUTD + k] = o[k];
}

extern "C" void kernel_launch(void* const* d_in, const int* in_sizes, int n_in,
                              void* d_out, int out_size, void* d_ws, size_t ws_size,
                              hipStream_t stream) {
    const float* x     = (const float*)d_in[0];
    const int*   ei    = (const int*)d_in[1];
    const float* eattr = (const float*)d_in[2];
    const float* W1    = (const float*)d_in[3];
    const float* as1   = (const float*)d_in[4];
    const float* ad1   = (const float*)d_in[5];
    const float* We1   = (const float*)d_in[6];
    const float* ae1   = (const float*)d_in[7];
    const float* b1    = (const float*)d_in[8];
    const float* W2    = (const float*)d_in[9];
    const float* as2   = (const float*)d_in[10];
    const float* ad2   = (const float*)d_in[11];
    const float* We2   = (const float*)d_in[12];
    const float* ae2   = (const float*)d_in[13];
    const float* b2    = (const float*)d_in[14];
    const float* D1w   = (const float*)d_in[15];
    const float* D1b   = (const float*)d_in[16];
    const float* D2w   = (const float*)d_in[17];
    const float* D2b   = (const float*)d_in[18];
    float* out = (float*)d_out;

    float* w = (float*)d_ws;
    size_t o = 0;
    // ---- zero-init region (one memset) ----
    float*    deg    = w + o; o += NN;
    float*    asum   = w + o; o += (size_t)NN * ED;
    unsigned* m1     = (unsigned*)(w + o); o += (size_t)NN * H1D;
    float*    denom1 = w + o; o += (size_t)NN * H1D;
    float*    acc1   = w + o; o += (size_t)NN * H1D * FD;   // becomes h1
    unsigned* m2     = (unsigned*)(w + o); o += NN;
    float*    denom2 = w + o; o += NN;
    float*    acc2   = w + o; o += (size_t)NN * FD;
    size_t zero_bytes = o * sizeof(float);
    // ---- compute-once region ----
    float* ve1     = w + o; o += 32;
    float* ve2     = w + o; o += 8;
    float* a_src1  = w + o; o += (size_t)NN * H1D;
    float* a_dst1  = w + o; o += (size_t)NN * H1D;
    float* a_edge1 = w + o; o += (size_t)EA * H1D;
    float* a_edge2 = w + o; o += EA;
    float* xh1     = w + o; o += (size_t)NN * H1D * FD;
    float* xh2     = w + o; o += (size_t)NN * FD;
    float* a_src2  = w + o; o += NN;
    float* a_dst2  = w + o; o += NN;

    hipMemsetAsync(d_ws, 0, zero_bytes, stream);

    const int B = 256;
    auto cdiv = [](long a, long b) { return (int)((a + b - 1) / b); };

    k_deg_attr<<<cdiv(EEg, B), B, 0, stream>>>(ei, eattr, deg, asum);
    k_ve<<<1, 64, 0, stream>>>(We1, ae1, We2, ae2, ve1, ve2);
    k_mean_self<<<cdiv(NN, B), B, 0, stream>>>(deg, asum, ve1, ve2, a_edge1, a_edge2);
    k_aedge<<<cdiv(EEg, B), B, 0, stream>>>(eattr, ve1, ve2, a_edge1, a_edge2);
    k_xh1<<<cdiv((long)NN * H1D * FD, B), B, 0, stream>>>(x, W1, xh1);
    k_attn1<<<cdiv((long)NN * H1D, B), B, 0, stream>>>(xh1, as1, ad1, a_src1, a_dst1);
    k_passA1<<<cdiv((long)EA * H1D, B), B, 0, stream>>>(ei, a_src1, a_dst1, a_edge1, m1);
    k_passB1<<<cdiv((long)EA * H1D, B), B, 0, stream>>>(ei, a_src1, a_dst1, a_edge1, m1, xh1,
                                                       denom1, acc1);
    k_norm1<<<cdiv((long)NN * H1D * FD, B), B, 0, stream>>>(acc1, denom1, b1);
    k_xh2<<<cdiv((long)NN * FD, B), B, 0, stream>>>(acc1, W2, xh2);
    k_attn2<<<cdiv(NN, B), B, 0, stream>>>(xh2, as2, ad2, a_src2, a_dst2);
    k_passA2<<<cdiv(EA, B), B, 0, stream>>>(ei, a_src2, a_dst2, a_edge2, m2);
    k_passB2<<<cdiv(EA, B), B, 0, stream>>>(ei, a_src2, a_dst2, a_edge2, m2, xh2, denom2, acc2);
    k_final<<<cdiv(NN, B), B, 0, stream>>>(acc2, denom2, b2, D1w, D1b, D2w, D2b, out);
}

// Round 2
// 1121.047 us; speedup vs baseline: 8.8052x; 8.8052x over previous
//
#include <hip/hip_runtime.h>

// Problem constants (match reference)
constexpr int NN  = 50000;
constexpr int EEg = 1600000;          // edges before self-loops
constexpr int IND = 16;
constexpr int FD  = 20;
constexpr int H1D = 4;
constexpr int ED  = 7;
constexpr int OUTD = 3;

__device__ __forceinline__ float lrelu(float x) { return x >= 0.0f ? x : 0.2f * x; }
__device__ __forceinline__ float elu(float x)   { return x > 0.0f ? x : expm1f(x); }

// ---- per-dst degree count (int atomics, real edges only) ----
__global__ void k_deg(const int* __restrict__ ei, int* __restrict__ deg) {
    int e = blockIdx.x * blockDim.x + threadIdx.x;
    if (e >= EEg) return;
    atomicAdd(&deg[ei[EEg + e]], 1);
}

// ---- tiny: ve1[d*4+h] = sum_f We1[d,h*F+f]*att_e1[h,f]; ve2[d] likewise ----
__global__ void k_ve(const float* __restrict__ We1, const float* __restrict__ ae1,
                     const float* __restrict__ We2, const float* __restrict__ ae2,
                     float* __restrict__ ve1, float* __restrict__ ve2) {
    int t = threadIdx.x;
    if (t < ED * H1D) {
        int d = t >> 2, h = t & 3;
        float s = 0.0f;
        for (int f = 0; f < FD; ++f) s += We1[d * (H1D * FD) + h * FD + f] * ae1[h * FD + f];
        ve1[t] = s;
    } else if (t < ED * H1D + ED) {
        int d = t - ED * H1D;
        float s = 0.0f;
        for (int f = 0; f < FD; ++f) s += We2[d * FD + f] * ae2[f];
        ve2[d] = s;
    }
}

// ---- single-block exclusive scan over deg -> row_off, cursor ----
__global__ void k_scan(const int* __restrict__ deg, int* __restrict__ row_off,
                       int* __restrict__ cursor) {
    __shared__ int sdata[1024];
    __shared__ int stotal;
    int tid = threadIdx.x;
    if (tid == 0) stotal = 0;
    __syncthreads();
    for (int base = 0; base < NN; base += 1024) {
        int i = base + tid;
        int v = (i < NN) ? deg[i] : 0;
        sdata[tid] = v;
        __syncthreads();
        for (int off = 1; off < 1024; off <<= 1) {
            int t = (tid >= off) ? sdata[tid - off] : 0;
            __syncthreads();
            sdata[tid] += t;
            __syncthreads();
        }
        if (i < NN) {
            int excl = stotal + sdata[tid] - v;
            row_off[i] = excl;
            cursor[i] = excl;
        }
        __syncthreads();
        if (tid == 0) stotal += sdata[1023];
        __syncthreads();
    }
    if (tid == 0) row_off[NN] = stotal;
}

// ---- scatter edges into CSR slots; compute a_edge in slot order; asum atomics ----
__global__ void k_scatter(const int* __restrict__ ei, const float* __restrict__ eattr,
                          const float* __restrict__ ve1, const float* __restrict__ ve2,
                          int* __restrict__ cursor, int* __restrict__ csr_src,
                          float* __restrict__ csr_ae1, float* __restrict__ csr_ae2,
                          float* __restrict__ asum) {
    int e = blockIdx.x * blockDim.x + threadIdx.x;
    if (e >= EEg) return;
    int src = ei[e], dst = ei[EEg + e];
    float a[ED];
#pragma unroll
    for (int d = 0; d < ED; ++d) a[d] = eattr[e * ED + d];
    int slot = atomicAdd(&cursor[dst], 1);
    csr_src[slot] = src;
#pragma unroll
    for (int h = 0; h < H1D; ++h) {
        float s = 0.0f;
#pragma unroll
        for (int d = 0; d < ED; ++d) s += a[d] * ve1[d * H1D + h];
        csr_ae1[(size_t)slot * H1D + h] = s;
    }
    float s2 = 0.0f;
#pragma unroll
    for (int d = 0; d < ED; ++d) s2 += a[d] * ve2[d];
    csr_ae2[slot] = s2;
#pragma unroll
    for (int d = 0; d < ED; ++d) atomicAdd(&asum[dst * ED + d], a[d]);
}

// ---- per-node: mean attr -> self-loop a_edge contribution for both layers ----
__global__ void k_mean_self(const int* __restrict__ deg, const float* __restrict__ asum,
                            const float* __restrict__ ve1, const float* __restrict__ ve2,
                            float* __restrict__ a_e1s, float* __restrict__ a_e2s) {
    int n = blockIdx.x * blockDim.x + threadIdx.x;
    if (n >= NN) return;
    float inv = 1.0f / fmaxf((float)deg[n], 1.0f);
    float m[ED];
#pragma unroll
    for (int d = 0; d < ED; ++d) m[d] = asum[n * ED + d] * inv;
#pragma unroll
    for (int h = 0; h < H1D; ++h) {
        float s = 0.0f;
#pragma unroll
        for (int d = 0; d < ED; ++d) s += m[d] * ve1[d * H1D + h];
        a_e1s[n * H1D + h] = s;
    }
    float s2 = 0.0f;
#pragma unroll
    for (int d = 0; d < ED; ++d) s2 += m[d] * ve2[d];
    a_e2s[n] = s2;
}

// ---- xh1 = x @ W1  ([N,16] @ [16,80]) ----
__global__ void k_xh1(const float* __restrict__ x, const float* __restrict__ W1,
                      float* __restrict__ xh1) {
    __shared__ float sW[IND * H1D * FD];
    for (int i = threadIdx.x; i < IND * H1D * FD; i += blockDim.x) sW[i] = W1[i];
    __syncthreads();
    int idx = blockIdx.x * blockDim.x + threadIdx.x;
    if (idx >= NN * H1D * FD) return;
    int n = idx / (H1D * FD), j = idx % (H1D * FD);
    const float* xr = &x[n * IND];
    float s = 0.0f;
#pragma unroll
    for (int k = 0; k < IND; ++k) s += xr[k] * sW[k * (H1D * FD) + j];
    xh1[idx] = s;
}

// ---- a_src1 / a_dst1 per (node, head) ----
__global__ void k_attn1(const float* __restrict__ xh1, const float* __restrict__ as,
                        const float* __restrict__ ad, float* __restrict__ a_src1,
                        float* __restrict__ a_dst1) {
    int idx = blockIdx.x * blockDim.x + threadIdx.x;
    if (idx >= NN * H1D) return;
    int n = idx >> 2, h = idx & 3;
    const float* xr = &xh1[(size_t)n * (H1D * FD) + h * FD];
    float ss = 0.0f, sd = 0.0f;
#pragma unroll
    for (int f = 0; f < FD; ++f) { float v = xr[f]; ss += v * as[h * FD + f]; sd += v * ad[h * FD + f]; }
    a_src1[idx] = ss; a_dst1[idx] = sd;
}

// ---- conv1: per (node, head) gather — max pass + softmax-accumulate pass ----
__global__ void k_conv1(const int* __restrict__ row_off, const int* __restrict__ csr_src,
                        const float* __restrict__ csr_ae1, const float* __restrict__ a_src1,
                        const float* __restrict__ a_dst1, const float* __restrict__ a_e1s,
                        const float* __restrict__ xh1, const float* __restrict__ b1,
                        float* __restrict__ h1) {
    int idx = blockIdx.x * blockDim.x + threadIdx.x;
    if (idx >= NN * H1D) return;
    int n = idx >> 2, h = idx & 3;
    int beg = row_off[n], end = row_off[n + 1];
    float adst = a_dst1[idx];
    float lself = lrelu(a_src1[idx] + adst + a_e1s[idx]);
    float m = lself;
    for (int j = beg; j < end; ++j) {
        int s = csr_src[j];
        float l = lrelu(a_src1[s * H1D + h] + adst + csr_ae1[(size_t)j * H1D + h]);
        m = fmaxf(m, l);
    }
    float denom = expf(lself - m);
    float acc[FD];
    const float* xself = &xh1[(size_t)n * (H1D * FD) + h * FD];
#pragma unroll
    for (int f = 0; f < FD; ++f) acc[f] = denom * xself[f];
    for (int j = beg; j < end; ++j) {
        int s = csr_src[j];
        float l = lrelu(a_src1[s * H1D + h] + adst + csr_ae1[(size_t)j * H1D + h]);
        float ex = expf(l - m);
        denom += ex;
        const float4* xr = (const float4*)&xh1[(size_t)s * (H1D * FD) + h * FD];
#pragma unroll
        for (int q = 0; q < FD / 4; ++q) {
            float4 v = xr[q];
            acc[q * 4 + 0] += ex * v.x;
            acc[q * 4 + 1] += ex * v.y;
            acc[q * 4 + 2] += ex * v.z;
            acc[q * 4 + 3] += ex * v.w;
        }
    }
    float inv = 1.0f / (denom + 1e-16f);
    float* ho = &h1[(size_t)n * (H1D * FD) + h * FD];
#pragma unroll
    for (int f = 0; f < FD; ++f) ho[f] = elu(acc[f] * inv + b1[h * FD + f]);
}

// ---- xh2 = h1 @ W2  ([N,80] @ [80,20]) ----
__global__ void k_xh2(const float* __restrict__ h1, const float* __restrict__ W2,
                      float* __restrict__ xh2) {
    __shared__ float sW[H1D * FD * FD];
    for (int i = threadIdx.x; i < H1D * FD * FD; i += blockDim.x) sW[i] = W2[i];
    __syncthreads();
    int idx = blockIdx.x * blockDim.x + threadIdx.x;
    if (idx >= NN * FD) return;
    int n = idx / FD, f = idx % FD;
    const float* hr = &h1[(size_t)n * (H1D * FD)];
    float s = 0.0f;
#pragma unroll
    for (int k = 0; k < H1D * FD; ++k) s += hr[k] * sW[k * FD + f];
    xh2[idx] = s;
}

// ---- a_src2 / a_dst2 per node ----
__global__ void k_attn2(const float* __restrict__ xh2, const float* __restrict__ as,
                        const float* __restrict__ ad, float* __restrict__ a_src2,
                        float* __restrict__ a_dst2) {
    int n = blockIdx.x * blockDim.x + threadIdx.x;
    if (n >= NN) return;
    const float* xr = &xh2[(size_t)n * FD];
    float ss = 0.0f, sd = 0.0f;
#pragma unroll
    for (int f = 0; f < FD; ++f) { float v = xr[f]; ss += v * as[f]; sd += v * ad[f]; }
    a_src2[n] = ss; a_dst2[n] = sd;
}

// ---- conv2 gather + normalize + elu + decoder MLP, all fused ----
__global__ void k_conv2dec(const int* __restrict__ row_off, const int* __restrict__ csr_src,
                           const float* __restrict__ csr_ae2, const float* __restrict__ a_src2,
                           const float* __restrict__ a_dst2, const float* __restrict__ a_e2s,
                           const float* __restrict__ xh2, const float* __restrict__ b2,
                           const float* __restrict__ D1w, const float* __restrict__ D1b,
                           const float* __restrict__ D2w, const float* __restrict__ D2b,
                           float* __restrict__ out) {
    __shared__ float sD1w[FD * 10], sD1b[10], sD2w[10 * OUTD], sD2b[OUTD], sb2[FD];
    for (int i = threadIdx.x; i < FD * 10; i += blockDim.x) sD1w[i] = D1w[i];
    if (threadIdx.x < 10) sD1b[threadIdx.x] = D1b[threadIdx.x];
    if (threadIdx.x < 10 * OUTD) sD2w[threadIdx.x] = D2w[threadIdx.x];
    if (threadIdx.x < OUTD) sD2b[threadIdx.x] = D2b[threadIdx.x];
    if (threadIdx.x < FD) sb2[threadIdx.x] = b2[threadIdx.x];
    __syncthreads();
    int n = blockIdx.x * blockDim.x + threadIdx.x;
    if (n >= NN) return;
    int beg = row_off[n], end = row_off[n + 1];
    float adst = a_dst2[n];
    float lself = lrelu(a_src2[n] + adst + a_e2s[n]);
    float m = lself;
    for (int j = beg; j < end; ++j) {
        int s = csr_src[j];
        float l = lrelu(a_src2[s] + adst + csr_ae2[j]);
        m = fmaxf(m, l);
    }
    float denom = expf(lself - m);
    float acc[FD];
    const float* xself = &xh2[(size_t)n * FD];
#pragma unroll
    for (int f = 0; f < FD; ++f) acc[f] = denom * xself[f];
    for (int j = beg; j < end; ++j) {
        int s = csr_src[j];
        float l = lrelu(a_src2[s] + adst + csr_ae2[j]);
        float ex = expf(l - m);
        denom += ex;
        const float4* xr = (const float4*)&xh2[(size_t)s * FD];
#pragma unroll
        for (int q = 0; q < FD / 4; ++q) {
            float4 v = xr[q];
            acc[q * 4 + 0] += ex * v.x;
            acc[q * 4 + 1] += ex * v.y;
            acc[q * 4 + 2] += ex * v.z;
            acc[q * 4 + 3] += ex * v.w;
        }
    }
    float inv = 1.0f / (denom + 1e-16f);
    float h2[FD];
#pragma unroll
    for (int f = 0; f < FD; ++f) h2[f] = elu(acc[f] * inv + sb2[f]);
    float o[OUTD];
#pragma unroll
    for (int k = 0; k < OUTD; ++k) o[k] = sD2b[k];
    for (int j = 0; j < 10; ++j) {
        float hid = sD1b[j];
#pragma unroll
        for (int f = 0; f < FD; ++f) hid += h2[f] * sD1w[f * 10 + j];
        hid = fmaxf(hid, 0.0f);
#pragma unroll
        for (int k = 0; k < OUTD; ++k) o[k] += hid * sD2w[j * OUTD + k];
    }
#pragma unroll
    for (int k = 0; k < OUTD; ++k) out[n * OUTD + k] = o[k];
}

extern "C" void kernel_launch(void* const* d_in, const int* in_sizes, int n_in,
                              void* d_out, int out_size, void* d_ws, size_t ws_size,
                              hipStream_t stream) {
    const float* x     = (const float*)d_in[0];
    const int*   ei    = (const int*)d_in[1];
    const float* eattr = (const float*)d_in[2];
    const float* W1    = (const float*)d_in[3];
    const float* as1   = (const float*)d_in[4];
    const float* ad1   = (const float*)d_in[5];
    const float* We1   = (const float*)d_in[6];
    const float* ae1   = (const float*)d_in[7];
    const float* b1    = (const float*)d_in[8];
    const float* W2    = (const float*)d_in[9];
    const float* as2   = (const float*)d_in[10];
    const float* ad2   = (const float*)d_in[11];
    const float* We2   = (const float*)d_in[12];
    const float* ae2   = (const float*)d_in[13];
    const float* b2    = (const float*)d_in[14];
    const float* D1w   = (const float*)d_in[15];
    const float* D1b   = (const float*)d_in[16];
    const float* D2w   = (const float*)d_in[17];
    const float* D2b   = (const float*)d_in[18];
    float* out = (float*)d_out;

    float* w = (float*)d_ws;
    size_t o = 0;
    // ---- zero-init region ----
    int*   deg    = (int*)(w + o); o += NN;
    int*   cursor = (int*)(w + o); o += NN;
    float* asum   = w + o; o += (size_t)NN * ED;
    size_t zero_bytes = o * sizeof(float);
    // ---- rest ----
    int*   row_off = (int*)(w + o); o += NN + 1;
    int*   csr_src = (int*)(w + o); o += EEg;
    float* csr_ae1 = w + o; o += (size_t)EEg * H1D;
    float* csr_ae2 = w + o; o += EEg;
    float* ve1     = w + o; o += 32;
    float* ve2     = w + o; o += 8;
    float* a_e1s   = w + o; o += (size_t)NN * H1D;
    float* a_e2s   = w + o; o += NN;
    float* a_src1  = w + o; o += (size_t)NN * H1D;
    float* a_dst1  = w + o; o += (size_t)NN * H1D;
    float* xh1     = w + o; o += (size_t)NN * H1D * FD;
    float* h1      = w + o; o += (size_t)NN * H1D * FD;
    float* xh2     = w + o; o += (size_t)NN * FD;
    float* a_src2  = w + o; o += NN;
    float* a_dst2  = w + o; o += NN;

    hipMemsetAsync(d_ws, 0, zero_bytes, stream);

    const int B = 256;
    auto cdiv = [](long a, long b) { return (int)((a + b - 1) / b); };

    k_deg<<<cdiv(EEg, B), B, 0, stream>>>(ei, deg);
    k_ve<<<1, 64, 0, stream>>>(We1, ae1, We2, ae2, ve1, ve2);
    k_scan<<<1, 1024, 0, stream>>>(deg, row_off, cursor);
    k_scatter<<<cdiv(EEg, B), B, 0, stream>>>(ei, eattr, ve1, ve2, cursor, csr_src,
                                              csr_ae1, csr_ae2, asum);
    k_mean_self<<<cdiv(NN, B), B, 0, stream>>>(deg, asum, ve1, ve2, a_e1s, a_e2s);
    k_xh1<<<cdiv((long)NN * H1D * FD, B), B, 0, stream>>>(x, W1, xh1);
    k_attn1<<<cdiv((long)NN * H1D, B), B, 0, stream>>>(xh1, as1, ad1, a_src1, a_dst1);
    k_conv1<<<cdiv((long)NN * H1D, B), B, 0, stream>>>(row_off, csr_src, csr_ae1, a_src1,
                                                       a_dst1, a_e1s, xh1, b1, h1);
    k_xh2<<<cdiv((long)NN * FD, B), B, 0, stream>>>(h1, W2, xh2);
    k_attn2<<<cdiv(NN, B), B, 0, stream>>>(xh2, as2, ad2, a_src2, a_dst2);
    k_conv2dec<<<cdiv(NN, B), B, 0, stream>>>(row_off, csr_src, csr_ae2, a_src2, a_dst2,
                                              a_e2s, xh2, b2, D1w, D1b, D2w, D2b, out);
}

// Round 3
// 390.997 us; speedup vs baseline: 25.2459x; 2.8672x over previous
//
#include <hip/hip_runtime.h>

// Problem constants (match reference)
constexpr int NN  = 50000;
constexpr int EEg = 1600000;          // edges before self-loops
constexpr int IND = 16;
constexpr int FD  = 20;
constexpr int H1D = 4;
constexpr int ED  = 7;
constexpr int OUTD = 3;

__device__ __forceinline__ float lrelu(float x) { return x >= 0.0f ? x : 0.2f * x; }
__device__ __forceinline__ float elu(float x)   { return x > 0.0f ? x : expm1f(x); }

// ---- per-dst degree histogram; atomic return value = edge rank within dst ----
__global__ void k_deg(const int* __restrict__ ei, int* __restrict__ deg,
                      int* __restrict__ rank) {
    int e = blockIdx.x * blockDim.x + threadIdx.x;
    if (e >= EEg) return;
    rank[e] = atomicAdd(&deg[ei[EEg + e]], 1);
}

// ---- tiny: ve1[d*4+h] = sum_f We1[d,h*F+f]*att_e1[h,f]; ve2[d] likewise ----
__global__ void k_ve(const float* __restrict__ We1, const float* __restrict__ ae1,
                     const float* __restrict__ We2, const float* __restrict__ ae2,
                     float* __restrict__ ve1, float* __restrict__ ve2) {
    int t = threadIdx.x;
    if (t < ED * H1D) {
        int d = t >> 2, h = t & 3;
        float s = 0.0f;
        for (int f = 0; f < FD; ++f) s += We1[d * (H1D * FD) + h * FD + f] * ae1[h * FD + f];
        ve1[t] = s;
    } else if (t < ED * H1D + ED) {
        int d = t - ED * H1D;
        float s = 0.0f;
        for (int f = 0; f < FD; ++f) s += We2[d * FD + f] * ae2[f];
        ve2[d] = s;
    }
}

// ---- two-level exclusive scan: A (per-block), B (block sums), C (add back) ----
__global__ void k_scanA(const int* __restrict__ deg, int* __restrict__ partial,
                        int* __restrict__ bsum) {
    __shared__ int sd[256];
    int t = threadIdx.x, i = blockIdx.x * 256 + t;
    int v = (i < NN) ? deg[i] : 0;
    sd[t] = v;
    __syncthreads();
    for (int off = 1; off < 256; off <<= 1) {
        int u = (t >= off) ? sd[t - off] : 0;
        __syncthreads();
        sd[t] += u;
        __syncthreads();
    }
    if (i < NN) partial[i] = sd[t] - v;
    if (t == 255) bsum[blockIdx.x] = sd[255];
}
__global__ void k_scanB(const int* __restrict__ bsum, int* __restrict__ boff, int nb) {
    __shared__ int sd[256];
    int t = threadIdx.x;
    int v = (t < nb) ? bsum[t] : 0;
    sd[t] = v;
    __syncthreads();
    for (int off = 1; off < 256; off <<= 1) {
        int u = (t >= off) ? sd[t - off] : 0;
        __syncthreads();
        sd[t] += u;
        __syncthreads();
    }
    if (t < nb) boff[t] = sd[t] - v;
}
__global__ void k_scanC(const int* __restrict__ partial, const int* __restrict__ boff,
                        int* __restrict__ row_off) {
    int i = blockIdx.x * 256 + threadIdx.x;
    if (i < NN) row_off[i] = partial[i] + boff[blockIdx.x];
    if (i == 0) row_off[NN] = EEg;
}

// ---- scatter: ONE aligned 32B record per edge, no atomics ----
// record: r0 = (src_bits, ae2, ae1_0, ae1_1), r1 = (ae1_2, ae1_3, 0, 0)
__global__ void k_scatter(const int* __restrict__ ei, const float* __restrict__ eattr,
                          const float* __restrict__ ve1, const float* __restrict__ ve2,
                          const int* __restrict__ row_off, const int* __restrict__ rank,
                          float4* __restrict__ csr) {
    __shared__ float sv1[ED * H1D], sv2[ED];
    if (threadIdx.x < ED * H1D) sv1[threadIdx.x] = ve1[threadIdx.x];
    if (threadIdx.x < ED) sv2[threadIdx.x] = ve2[threadIdx.x];
    __syncthreads();
    int e = blockIdx.x * blockDim.x + threadIdx.x;
    if (e >= EEg) return;
    int src = ei[e], dst = ei[EEg + e];
    float a[ED];
#pragma unroll
    for (int d = 0; d < ED; ++d) a[d] = eattr[e * ED + d];
    float v0 = 0.f, v1 = 0.f, v2 = 0.f, v3 = 0.f, w2 = 0.f;
#pragma unroll
    for (int d = 0; d < ED; ++d) {
        v0 += a[d] * sv1[d * H1D + 0];
        v1 += a[d] * sv1[d * H1D + 1];
        v2 += a[d] * sv1[d * H1D + 2];
        v3 += a[d] * sv1[d * H1D + 3];
        w2 += a[d] * sv2[d];
    }
    int slot = row_off[dst] + rank[e];
    csr[(size_t)slot * 2]     = make_float4(__int_as_float(src), w2, v0, v1);
    csr[(size_t)slot * 2 + 1] = make_float4(v2, v3, 0.0f, 0.0f);
}

// ---- per-node self-loop attention terms = mean of stored ae over CSR range ----
__global__ void k_mean_self(const int* __restrict__ row_off, const float4* __restrict__ csr,
                            float* __restrict__ a_e1s, float* __restrict__ a_e2s) {
    int n = blockIdx.x * blockDim.x + threadIdx.x;
    if (n >= NN) return;
    int beg = row_off[n], end = row_off[n + 1];
    float s0 = 0.f, s1 = 0.f, s2 = 0.f, s3 = 0.f, se = 0.f;
    for (int j = beg; j < end; ++j) {
        float4 r0 = csr[(size_t)j * 2];
        float4 r1 = csr[(size_t)j * 2 + 1];
        se += r0.y; s0 += r0.z; s1 += r0.w; s2 += r1.x; s3 += r1.y;
    }
    float inv = 1.0f / fmaxf((float)(end - beg), 1.0f);
    a_e1s[n * H1D + 0] = s0 * inv;
    a_e1s[n * H1D + 1] = s1 * inv;
    a_e1s[n * H1D + 2] = s2 * inv;
    a_e1s[n * H1D + 3] = s3 * inv;
    a_e2s[n] = se * inv;
}

// ---- xh1 = x @ W1 fused with a_src1/a_dst1 dots; thread per (n,h) ----
__global__ void k_xh1attn1(const float* __restrict__ x, const float* __restrict__ W1,
                           const float* __restrict__ as, const float* __restrict__ ad,
                           float* __restrict__ xh1, float* __restrict__ a_src1,
                           float* __restrict__ a_dst1) {
    __shared__ float sW[IND * H1D * FD];
    for (int i = threadIdx.x; i < IND * H1D * FD; i += blockDim.x) sW[i] = W1[i];
    __syncthreads();
    int idx = blockIdx.x * blockDim.x + threadIdx.x;
    if (idx >= NN * H1D) return;
    int n = idx >> 2, h = idx & 3;
    float xr[IND];
    const float4* xp = (const float4*)&x[(size_t)n * IND];
#pragma unroll
    for (int q = 0; q < IND / 4; ++q) {
        float4 v = xp[q];
        xr[4 * q] = v.x; xr[4 * q + 1] = v.y; xr[4 * q + 2] = v.z; xr[4 * q + 3] = v.w;
    }
    float ss = 0.f, sd = 0.f;
    float4* xo = (float4*)&xh1[(size_t)n * (H1D * FD) + h * FD];
    float outv[FD];
#pragma unroll
    for (int f = 0; f < FD; ++f) {
        float s = 0.f;
#pragma unroll
        for (int k = 0; k < IND; ++k) s += xr[k] * sW[k * (H1D * FD) + h * FD + f];
        outv[f] = s;
        ss += s * as[h * FD + f];
        sd += s * ad[h * FD + f];
    }
#pragma unroll
    for (int q = 0; q < FD / 4; ++q)
        xo[q] = make_float4(outv[4 * q], outv[4 * q + 1], outv[4 * q + 2], outv[4 * q + 3]);
    a_src1[idx] = ss; a_dst1[idx] = sd;
}

// ---- conv1: per (node, head) gather, single-pass online softmax ----
__global__ void k_conv1(const int* __restrict__ row_off, const float4* __restrict__ csr,
                        const float* __restrict__ a_src1, const float* __restrict__ a_dst1,
                        const float* __restrict__ a_e1s, const float* __restrict__ xh1,
                        const float* __restrict__ b1, float* __restrict__ h1) {
    int idx = blockIdx.x * blockDim.x + threadIdx.x;
    if (idx >= NN * H1D) return;
    int n = idx >> 2, h = idx & 3;
    int beg = row_off[n], end = row_off[n + 1];
    float adst = a_dst1[idx];
    float m = lrelu(a_src1[idx] + adst + a_e1s[idx]);   // self-loop logit
    float denom = 1.0f;
    float acc[FD];
    const float4* xs = (const float4*)&xh1[(size_t)n * (H1D * FD) + h * FD];
#pragma unroll
    for (int q = 0; q < FD / 4; ++q) {
        float4 v = xs[q];
        acc[4 * q] = v.x; acc[4 * q + 1] = v.y; acc[4 * q + 2] = v.z; acc[4 * q + 3] = v.w;
    }
    for (int j = beg; j < end; ++j) {
        float4 r0 = csr[(size_t)j * 2];
        float4 r1 = csr[(size_t)j * 2 + 1];
        int s = __float_as_int(r0.x);
        float ae = (h == 0) ? r0.z : (h == 1) ? r0.w : (h == 2) ? r1.x : r1.y;
        float l = lrelu(a_src1[s * H1D + h] + adst + ae);
        if (l > m) {
            float sc = expf(m - l);
            denom *= sc;
#pragma unroll
            for (int f = 0; f < FD; ++f) acc[f] *= sc;
            m = l;
        }
        float ex = expf(l - m);
        denom += ex;
        const float4* xr = (const float4*)&xh1[(size_t)s * (H1D * FD) + h * FD];
#pragma unroll
        for (int q = 0; q < FD / 4; ++q) {
            float4 v = xr[q];
            acc[4 * q]     += ex * v.x;
            acc[4 * q + 1] += ex * v.y;
            acc[4 * q + 2] += ex * v.z;
            acc[4 * q + 3] += ex * v.w;
        }
    }
    float inv = 1.0f / (denom + 1e-16f);
    float* ho = &h1[(size_t)n * (H1D * FD) + h * FD];
#pragma unroll
    for (int f = 0; f < FD; ++f) ho[f] = elu(acc[f] * inv + b1[h * FD + f]);
}

// ---- xh2 = h1 @ W2 fused with a_src2/a_dst2; thread per node ----
__global__ void k_xh2attn2(const float* __restrict__ h1, const float* __restrict__ W2,
                           const float* __restrict__ as, const float* __restrict__ ad,
                           float* __restrict__ xh2, float* __restrict__ a_src2,
                           float* __restrict__ a_dst2) {
    __shared__ float sW[H1D * FD * FD];
    for (int i = threadIdx.x; i < H1D * FD * FD; i += blockDim.x) sW[i] = W2[i];
    __syncthreads();
    int n = blockIdx.x * blockDim.x + threadIdx.x;
    if (n >= NN) return;
    float hr[H1D * FD];
    const float4* hp = (const float4*)&h1[(size_t)n * (H1D * FD)];
#pragma unroll
    for (int q = 0; q < (H1D * FD) / 4; ++q) {
        float4 v = hp[q];
        hr[4 * q] = v.x; hr[4 * q + 1] = v.y; hr[4 * q + 2] = v.z; hr[4 * q + 3] = v.w;
    }
    float ss = 0.f, sd = 0.f;
    float outv[FD];
#pragma unroll
    for (int f = 0; f < FD; ++f) {
        float s = 0.f;
#pragma unroll
        for (int k = 0; k < H1D * FD; ++k) s += hr[k] * sW[k * FD + f];
        outv[f] = s;
        ss += s * as[f];
        sd += s * ad[f];
    }
    float4* xo = (float4*)&xh2[(size_t)n * FD];
#pragma unroll
    for (int q = 0; q < FD / 4; ++q)
        xo[q] = make_float4(outv[4 * q], outv[4 * q + 1], outv[4 * q + 2], outv[4 * q + 3]);
    a_src2[n] = ss; a_dst2[n] = sd;
}

// ---- conv2 gather (online softmax) + elu + decoder MLP, fused; thread per node ----
__global__ void k_conv2dec(const int* __restrict__ row_off, const float4* __restrict__ csr,
                           const float* __restrict__ a_src2, const float* __restrict__ a_dst2,
                           const float* __restrict__ a_e2s, const float* __restrict__ xh2,
                           const float* __restrict__ b2, const float* __restrict__ D1w,
                           const float* __restrict__ D1b, const float* __restrict__ D2w,
                           const float* __restrict__ D2b, float* __restrict__ out) {
    __shared__ float sD1w[FD * 10], sD1b[10], sD2w[10 * OUTD], sD2b[OUTD], sb2[FD];
    for (int i = threadIdx.x; i < FD * 10; i += blockDim.x) sD1w[i] = D1w[i];
    if (threadIdx.x < 10) sD1b[threadIdx.x] = D1b[threadIdx.x];
    if (threadIdx.x < 10 * OUTD) sD2w[threadIdx.x] = D2w[threadIdx.x];
    if (threadIdx.x < OUTD) sD2b[threadIdx.x] = D2b[threadIdx.x];
    if (threadIdx.x < FD) sb2[threadIdx.x] = b2[threadIdx.x];
    __syncthreads();
    int n = blockIdx.x * blockDim.x + threadIdx.x;
    if (n >= NN) return;
    int beg = row_off[n], end = row_off[n + 1];
    float adst = a_dst2[n];
    float m = lrelu(a_src2[n] + adst + a_e2s[n]);
    float denom = 1.0f;
    float acc[FD];
    const float4* xs = (const float4*)&xh2[(size_t)n * FD];
#pragma unroll
    for (int q = 0; q < FD / 4; ++q) {
        float4 v = xs[q];
        acc[4 * q] = v.x; acc[4 * q + 1] = v.y; acc[4 * q + 2] = v.z; acc[4 * q + 3] = v.w;
    }
    for (int j = beg; j < end; ++j) {
        float4 r0 = csr[(size_t)j * 2];
        int s = __float_as_int(r0.x);
        float l = lrelu(a_src2[s] + adst + r0.y);
        if (l > m) {
            float sc = expf(m - l);
            denom *= sc;
#pragma unroll
            for (int f = 0; f < FD; ++f) acc[f] *= sc;
            m = l;
        }
        float ex = expf(l - m);
        denom += ex;
        const float4* xr = (const float4*)&xh2[(size_t)s * FD];
#pragma unroll
        for (int q = 0; q < FD / 4; ++q) {
            float4 v = xr[q];
            acc[4 * q]     += ex * v.x;
            acc[4 * q + 1] += ex * v.y;
            acc[4 * q + 2] += ex * v.z;
            acc[4 * q + 3] += ex * v.w;
        }
    }
    float inv = 1.0f / (denom + 1e-16f);
    float h2[FD];
#pragma unroll
    for (int f = 0; f < FD; ++f) h2[f] = elu(acc[f] * inv + sb2[f]);
    float o[OUTD];
#pragma unroll
    for (int k = 0; k < OUTD; ++k) o[k] = sD2b[k];
    for (int j = 0; j < 10; ++j) {
        float hid = sD1b[j];
#pragma unroll
        for (int f = 0; f < FD; ++f) hid += h2[f] * sD1w[f * 10 + j];
        hid = fmaxf(hid, 0.0f);
#pragma unroll
        for (int k = 0; k < OUTD; ++k) o[k] += hid * sD2w[j * OUTD + k];
    }
#pragma unroll
    for (int k = 0; k < OUTD; ++k) out[n * OUTD + k] = o[k];
}

extern "C" void kernel_launch(void* const* d_in, const int* in_sizes, int n_in,
                              void* d_out, int out_size, void* d_ws, size_t ws_size,
                              hipStream_t stream) {
    const float* x     = (const float*)d_in[0];
    const int*   ei    = (const int*)d_in[1];
    const float* eattr = (const float*)d_in[2];
    const float* W1    = (const float*)d_in[3];
    const float* as1   = (const float*)d_in[4];
    const float* ad1   = (const float*)d_in[5];
    const float* We1   = (const float*)d_in[6];
    const float* ae1   = (const float*)d_in[7];
    const float* b1    = (const float*)d_in[8];
    const float* W2    = (const float*)d_in[9];
    const float* as2   = (const float*)d_in[10];
    const float* ad2   = (const float*)d_in[11];
    const float* We2   = (const float*)d_in[12];
    const float* ae2   = (const float*)d_in[13];
    const float* b2    = (const float*)d_in[14];
    const float* D1w   = (const float*)d_in[15];
    const float* D1b   = (const float*)d_in[16];
    const float* D2w   = (const float*)d_in[17];
    const float* D2b   = (const float*)d_in[18];
    float* out = (float*)d_out;

    float* w = (float*)d_ws;
    size_t o = 0;
    // ---- zero-init region: only deg ----
    int*   deg = (int*)(w + o); o += NN;
    size_t zero_bytes = o * sizeof(float);
    // ---- rest (fully overwritten each call) ----
    int*   rank    = (int*)(w + o); o += EEg;
    int*   partial = (int*)(w + o); o += NN;
    int*   bsum    = (int*)(w + o); o += 256;
    int*   boff    = (int*)(w + o); o += 256;
    int*   row_off = (int*)(w + o); o += NN + 4;
    float* csr     = w + o; o += (size_t)EEg * 8;          // 32B records
    float* ve1     = w + o; o += 32;
    float* ve2     = w + o; o += 8;
    float* a_e1s   = w + o; o += (size_t)NN * H1D;
    float* a_e2s   = w + o; o += NN;
    float* a_src1  = w + o; o += (size_t)NN * H1D;
    float* a_dst1  = w + o; o += (size_t)NN * H1D;
    float* xh1     = w + o; o += (size_t)NN * H1D * FD;
    float* h1      = w + o; o += (size_t)NN * H1D * FD;
    float* xh2     = w + o; o += (size_t)NN * FD;
    float* a_src2  = w + o; o += NN;
    float* a_dst2  = w + o; o += NN;

    hipMemsetAsync(d_ws, 0, zero_bytes, stream);

    const int B = 256;
    auto cdiv = [](long a, long b) { return (int)((a + b - 1) / b); };
    const int NB = cdiv(NN, 256);   // 196 blocks for node-sized scans

    k_deg<<<cdiv(EEg, B), B, 0, stream>>>(ei, deg, rank);
    k_ve<<<1, 64, 0, stream>>>(We1, ae1, We2, ae2, ve1, ve2);
    k_scanA<<<NB, 256, 0, stream>>>(deg, partial, bsum);
    k_scanB<<<1, 256, 0, stream>>>(bsum, boff, NB);
    k_scanC<<<NB, 256, 0, stream>>>(partial, boff, row_off);
    k_scatter<<<cdiv(EEg, B), B, 0, stream>>>(ei, eattr, ve1, ve2, row_off, rank,
                                              (float4*)csr);
    k_mean_self<<<cdiv(NN, B), B, 0, stream>>>(row_off, (const float4*)csr, a_e1s, a_e2s);
    k_xh1attn1<<<cdiv((long)NN * H1D, B), B, 0, stream>>>(x, W1, as1, ad1, xh1, a_src1,
                                                          a_dst1);
    k_conv1<<<cdiv((long)NN * H1D, B), B, 0, stream>>>(row_off, (const float4*)csr, a_src1,
                                                       a_dst1, a_e1s, xh1, b1, h1);
    k_xh2attn2<<<cdiv(NN, B), B, 0, stream>>>(h1, W2, as2, ad2, xh2, a_src2, a_dst2);
    k_conv2dec<<<cdiv(NN, B), B, 0, stream>>>(row_off, (const float4*)csr, a_src2, a_dst2,
                                              a_e2s, xh2, b2, D1w, D1b, D2w, D2b, out);
}

// Round 4
// 280.792 us; speedup vs baseline: 35.1545x; 1.3925x over previous
//
#include <hip/hip_runtime.h>
#include <hip/hip_fp16.h>

// Problem constants (match reference)
constexpr int NN  = 50000;
constexpr int EEg = 1600000;          // edges before self-loops
constexpr int IND = 16;
constexpr int FD  = 20;
constexpr int H1D = 4;
constexpr int ED  = 7;
constexpr int OUTD = 3;
constexpr int FP  = 24;               // padded half-row (20 -> 24 halfs = 48B)

__device__ __forceinline__ float lrelu(float x) { return x >= 0.0f ? x : 0.2f * x; }
__device__ __forceinline__ float elu(float x)   { return x > 0.0f ? x : expm1f(x); }
__device__ __forceinline__ unsigned pack2(float a, float b) {
    __half2 h = __floats2half2_rn(a, b);
    return *(unsigned*)&h;
}
__device__ __forceinline__ float2 up2(unsigned w) {
    __half2 h = *(__half2*)&w;
    return __half22float2(h);
}

// ---- per-dst degree histogram; atomic return value = edge rank within dst ----
__global__ void k_deg(const int* __restrict__ ei, int* __restrict__ deg,
                      int* __restrict__ rank) {
    int e = blockIdx.x * blockDim.x + threadIdx.x;
    if (e >= EEg) return;
    rank[e] = atomicAdd(&deg[ei[EEg + e]], 1);
}

// ---- tiny: ve1[d*4+h] = sum_f We1[d,h*F+f]*att_e1[h,f]; ve2[d] likewise ----
__global__ void k_ve(const float* __restrict__ We1, const float* __restrict__ ae1,
                     const float* __restrict__ We2, const float* __restrict__ ae2,
                     float* __restrict__ ve1, float* __restrict__ ve2) {
    int t = threadIdx.x;
    if (t < ED * H1D) {
        int d = t >> 2, h = t & 3;
        float s = 0.0f;
        for (int f = 0; f < FD; ++f) s += We1[d * (H1D * FD) + h * FD + f] * ae1[h * FD + f];
        ve1[t] = s;
    } else if (t < ED * H1D + ED) {
        int d = t - ED * H1D;
        float s = 0.0f;
        for (int f = 0; f < FD; ++f) s += We2[d * FD + f] * ae2[f];
        ve2[d] = s;
    }
}

// ---- two-level exclusive scan ----
__global__ void k_scanA(const int* __restrict__ deg, int* __restrict__ partial,
                        int* __restrict__ bsum) {
    __shared__ int sd[256];
    int t = threadIdx.x, i = blockIdx.x * 256 + t;
    int v = (i < NN) ? deg[i] : 0;
    sd[t] = v;
    __syncthreads();
    for (int off = 1; off < 256; off <<= 1) {
        int u = (t >= off) ? sd[t - off] : 0;
        __syncthreads();
        sd[t] += u;
        __syncthreads();
    }
    if (i < NN) partial[i] = sd[t] - v;
    if (t == 255) bsum[blockIdx.x] = sd[255];
}
__global__ void k_scanB(const int* __restrict__ bsum, int* __restrict__ boff, int nb) {
    __shared__ int sd[256];
    int t = threadIdx.x;
    int v = (t < nb) ? bsum[t] : 0;
    sd[t] = v;
    __syncthreads();
    for (int off = 1; off < 256; off <<= 1) {
        int u = (t >= off) ? sd[t - off] : 0;
        __syncthreads();
        sd[t] += u;
        __syncthreads();
    }
    if (t < nb) boff[t] = sd[t] - v;
}
__global__ void k_scanC(const int* __restrict__ partial, const int* __restrict__ boff,
                        int* __restrict__ row_off) {
    int i = blockIdx.x * 256 + threadIdx.x;
    if (i < NN) row_off[i] = partial[i] + boff[blockIdx.x];
    if (i == 0) row_off[NN] = EEg;
}

// ---- scatter: ONE aligned 16B record per edge, no atomics ----
// record: {x=src, y=half2(ae1_0,ae1_1), z=half2(ae1_2,ae1_3), w=half2(ae2,0)}
__global__ void k_scatter(const int* __restrict__ ei, const float* __restrict__ eattr,
                          const float* __restrict__ ve1, const float* __restrict__ ve2,
                          const int* __restrict__ row_off, const int* __restrict__ rank,
                          uint4* __restrict__ csr) {
    __shared__ float sv1[ED * H1D], sv2[ED];
    if (threadIdx.x < ED * H1D) sv1[threadIdx.x] = ve1[threadIdx.x];
    if (threadIdx.x < ED) sv2[threadIdx.x] = ve2[threadIdx.x];
    __syncthreads();
    int e = blockIdx.x * blockDim.x + threadIdx.x;
    if (e >= EEg) return;
    int src = ei[e], dst = ei[EEg + e];
    float a[ED];
#pragma unroll
    for (int d = 0; d < ED; ++d) a[d] = eattr[e * ED + d];
    float v0 = 0.f, v1 = 0.f, v2 = 0.f, v3 = 0.f, w2 = 0.f;
#pragma unroll
    for (int d = 0; d < ED; ++d) {
        v0 += a[d] * sv1[d * H1D + 0];
        v1 += a[d] * sv1[d * H1D + 1];
        v2 += a[d] * sv1[d * H1D + 2];
        v3 += a[d] * sv1[d * H1D + 3];
        w2 += a[d] * sv2[d];
    }
    int slot = row_off[dst] + rank[e];
    uint4 rec;
    rec.x = (unsigned)src;
    rec.y = pack2(v0, v1);
    rec.z = pack2(v2, v3);
    rec.w = pack2(w2, 0.0f);
    csr[slot] = rec;
}

// ---- per-node self-loop attention terms = mean of stored ae over CSR range ----
__global__ void k_mean_self(const int* __restrict__ row_off, const uint4* __restrict__ csr,
                            float* __restrict__ a_e1s, float* __restrict__ a_e2s) {
    int n = blockIdx.x * blockDim.x + threadIdx.x;
    if (n >= NN) return;
    int beg = row_off[n], end = row_off[n + 1];
    float s0 = 0.f, s1 = 0.f, s2 = 0.f, s3 = 0.f, se = 0.f;
    for (int j = beg; j < end; ++j) {
        uint4 r = csr[j];
        float2 a01 = up2(r.y), a23 = up2(r.z), ap = up2(r.w);
        s0 += a01.x; s1 += a01.y; s2 += a23.x; s3 += a23.y; se += ap.x;
    }
    float inv = 1.0f / fmaxf((float)(end - beg), 1.0f);
    a_e1s[n * H1D + 0] = s0 * inv;
    a_e1s[n * H1D + 1] = s1 * inv;
    a_e1s[n * H1D + 2] = s2 * inv;
    a_e1s[n * H1D + 3] = s3 * inv;
    a_e2s[n] = se * inv;
}

// ---- xh1 = x @ W1 fused with attn dots; fp16 padded rows out; thread per (n,h) ----
__global__ void k_xh1attn1(const float* __restrict__ x, const float* __restrict__ W1,
                           const float* __restrict__ as, const float* __restrict__ ad,
                           __half* __restrict__ xh1h, float* __restrict__ a_src1,
                           float* __restrict__ a_dst1) {
    __shared__ float sW[IND * H1D * FD];
    for (int i = threadIdx.x; i < IND * H1D * FD; i += blockDim.x) sW[i] = W1[i];
    __syncthreads();
    int idx = blockIdx.x * blockDim.x + threadIdx.x;
    if (idx >= NN * H1D) return;
    int n = idx >> 2, h = idx & 3;
    float xr[IND];
    const float4* xp = (const float4*)&x[(size_t)n * IND];
#pragma unroll
    for (int q = 0; q < IND / 4; ++q) {
        float4 v = xp[q];
        xr[4 * q] = v.x; xr[4 * q + 1] = v.y; xr[4 * q + 2] = v.z; xr[4 * q + 3] = v.w;
    }
    float ss = 0.f, sd = 0.f;
    float o[FD];
#pragma unroll
    for (int f = 0; f < FD; ++f) {
        float s = 0.f;
#pragma unroll
        for (int k = 0; k < IND; ++k) s += xr[k] * sW[k * (H1D * FD) + h * FD + f];
        o[f] = s;
        ss += s * as[h * FD + f];
        sd += s * ad[h * FD + f];
    }
    uint4* xo = (uint4*)&xh1h[((size_t)n * H1D + h) * FP];
    xo[0] = make_uint4(pack2(o[0], o[1]), pack2(o[2], o[3]), pack2(o[4], o[5]), pack2(o[6], o[7]));
    xo[1] = make_uint4(pack2(o[8], o[9]), pack2(o[10], o[11]), pack2(o[12], o[13]), pack2(o[14], o[15]));
    xo[2] = make_uint4(pack2(o[16], o[17]), pack2(o[18], o[19]), 0u, 0u);
    a_src1[idx] = ss; a_dst1[idx] = sd;
}

#define GATHER_ACC(ex, base)                                            \
    {                                                                   \
        const uint4* xr_ = (const uint4*)(base);                        \
        uint4 g0 = xr_[0], g1 = xr_[1];                                 \
        uint2 g2 = *(const uint2*)(xr_ + 2);                            \
        float2 f_;                                                      \
        f_ = up2(g0.x); acc[0] += (ex) * f_.x;  acc[1] += (ex) * f_.y;  \
        f_ = up2(g0.y); acc[2] += (ex) * f_.x;  acc[3] += (ex) * f_.y;  \
        f_ = up2(g0.z); acc[4] += (ex) * f_.x;  acc[5] += (ex) * f_.y;  \
        f_ = up2(g0.w); acc[6] += (ex) * f_.x;  acc[7] += (ex) * f_.y;  \
        f_ = up2(g1.x); acc[8] += (ex) * f_.x;  acc[9] += (ex) * f_.y;  \
        f_ = up2(g1.y); acc[10] += (ex) * f_.x; acc[11] += (ex) * f_.y; \
        f_ = up2(g1.z); acc[12] += (ex) * f_.x; acc[13] += (ex) * f_.y; \
        f_ = up2(g1.w); acc[14] += (ex) * f_.x; acc[15] += (ex) * f_.y; \
        f_ = up2(g2.x); acc[16] += (ex) * f_.x; acc[17] += (ex) * f_.y; \
        f_ = up2(g2.y); acc[18] += (ex) * f_.x; acc[19] += (ex) * f_.y; \
    }

// ---- conv1: 8 lanes per node (4 heads x 2 edge-splits), online softmax + merge ----
__global__ __launch_bounds__(64) void k_conv1(
        const int* __restrict__ row_off, const uint4* __restrict__ csr,
        const float* __restrict__ a_src1, const float* __restrict__ a_dst1,
        const float* __restrict__ a_e1s, const __half* __restrict__ xh1h,
        const float* __restrict__ b1, float* __restrict__ h1) {
    int idx = blockIdx.x * 64 + threadIdx.x;      // [0, NN*8)
    int n = idx >> 3, h = idx & 3, p = (idx >> 2) & 1;
    int beg = row_off[n], end = row_off[n + 1];
    float adst = a_dst1[n * H1D + h];
    float m, denom;
    float acc[FD];
    if (p == 0) {
        m = lrelu(a_src1[n * H1D + h] + adst + a_e1s[n * H1D + h]);
        denom = 1.0f;
#pragma unroll
        for (int f = 0; f < FD; ++f) acc[f] = 0.f;
        GATHER_ACC(1.0f, &xh1h[((size_t)n * H1D + h) * FP]);
    } else {
        m = -1e30f; denom = 0.f;
#pragma unroll
        for (int f = 0; f < FD; ++f) acc[f] = 0.f;
    }
    for (int j = beg + p; j < end; j += 2) {
        uint4 r = csr[j];
        int s = (int)r.x;
        unsigned w = (h < 2) ? r.y : r.z;
        float2 aep = up2(w);
        float ae = (h & 1) ? aep.y : aep.x;
        float l = lrelu(a_src1[s * H1D + h] + adst + ae);
        if (l > m) {
            float sc = expf(m - l);
            denom *= sc;
#pragma unroll
            for (int f = 0; f < FD; ++f) acc[f] *= sc;
            m = l;
        }
        float ex = expf(l - m);
        denom += ex;
        GATHER_ACC(ex, &xh1h[((size_t)s * H1D + h) * FP]);
    }
    // merge the two edge-split partials (lanes differ in bit 2)
    float mo = __shfl_xor(m, 4);
    float dno = __shfl_xor(denom, 4);
    float M = fmaxf(m, mo);
    float ssf = expf(m - M), sof = expf(mo - M);
    denom = denom * ssf + dno * sof;
#pragma unroll
    for (int f = 0; f < FD; ++f) acc[f] = acc[f] * ssf + __shfl_xor(acc[f], 4) * sof;
    if (p) return;
    float inv = 1.0f / (denom + 1e-16f);
    float* ho = &h1[((size_t)n * H1D + h) * FD];
#pragma unroll
    for (int f = 0; f < FD; ++f) ho[f] = elu(acc[f] * inv + b1[h * FD + f]);
}

// ---- xh2 = h1 @ W2 fused with attn dots; fp16 padded row out; thread per node ----
__global__ void k_xh2attn2(const float* __restrict__ h1, const float* __restrict__ W2,
                           const float* __restrict__ as, const float* __restrict__ ad,
                           __half* __restrict__ xh2h, float* __restrict__ a_src2,
                           float* __restrict__ a_dst2) {
    __shared__ float sW[H1D * FD * FD];
    for (int i = threadIdx.x; i < H1D * FD * FD; i += blockDim.x) sW[i] = W2[i];
    __syncthreads();
    int n = blockIdx.x * blockDim.x + threadIdx.x;
    if (n >= NN) return;
    float hr[H1D * FD];
    const float4* hp = (const float4*)&h1[(size_t)n * (H1D * FD)];
#pragma unroll
    for (int q = 0; q < (H1D * FD) / 4; ++q) {
        float4 v = hp[q];
        hr[4 * q] = v.x; hr[4 * q + 1] = v.y; hr[4 * q + 2] = v.z; hr[4 * q + 3] = v.w;
    }
    float ss = 0.f, sd = 0.f;
    float o[FD];
#pragma unroll
    for (int f = 0; f < FD; ++f) {
        float s = 0.f;
#pragma unroll
        for (int k = 0; k < H1D * FD; ++k) s += hr[k] * sW[k * FD + f];
        o[f] = s;
        ss += s * as[f];
        sd += s * ad[f];
    }
    uint4* xo = (uint4*)&xh2h[(size_t)n * FP];
    xo[0] = make_uint4(pack2(o[0], o[1]), pack2(o[2], o[3]), pack2(o[4], o[5]), pack2(o[6], o[7]));
    xo[1] = make_uint4(pack2(o[8], o[9]), pack2(o[10], o[11]), pack2(o[12], o[13]), pack2(o[14], o[15]));
    xo[2] = make_uint4(pack2(o[16], o[17]), pack2(o[18], o[19]), 0u, 0u);
    a_src2[n] = ss; a_dst2[n] = sd;
}

// ---- conv2 (2 lanes/node edge-split) + elu + decoder MLP ----
__global__ __launch_bounds__(64) void k_conv2dec(
        const int* __restrict__ row_off, const uint4* __restrict__ csr,
        const float* __restrict__ a_src2, const float* __restrict__ a_dst2,
        const float* __restrict__ a_e2s, const __half* __restrict__ xh2h,
        const float* __restrict__ b2, const float* __restrict__ D1w,
        const float* __restrict__ D1b, const float* __restrict__ D2w,
        const float* __restrict__ D2b, float* __restrict__ out) {
    __shared__ float sD1w[FD * 10], sD1b[10], sD2w[10 * OUTD], sD2b[OUTD], sb2[FD];
    for (int i = threadIdx.x; i < FD * 10; i += blockDim.x) sD1w[i] = D1w[i];
    if (threadIdx.x < 10) sD1b[threadIdx.x] = D1b[threadIdx.x];
    if (threadIdx.x < 10 * OUTD) sD2w[threadIdx.x] = D2w[threadIdx.x];
    if (threadIdx.x < OUTD) sD2b[threadIdx.x] = D2b[threadIdx.x];
    if (threadIdx.x < FD) sb2[threadIdx.x] = b2[threadIdx.x];
    __syncthreads();
    int idx = blockIdx.x * 64 + threadIdx.x;      // [0, NN*2)
    if (idx >= NN * 2) return;
    int n = idx >> 1, p = idx & 1;
    int beg = row_off[n], end = row_off[n + 1];
    float adst = a_dst2[n];
    float m, denom;
    float acc[FD];
    if (p == 0) {
        m = lrelu(a_src2[n] + adst + a_e2s[n]);
        denom = 1.0f;
#pragma unroll
        for (int f = 0; f < FD; ++f) acc[f] = 0.f;
        GATHER_ACC(1.0f, &xh2h[(size_t)n * FP]);
    } else {
        m = -1e30f; denom = 0.f;
#pragma unroll
        for (int f = 0; f < FD; ++f) acc[f] = 0.f;
    }
    for (int j = beg + p; j < end; j += 2) {
        uint4 r = csr[j];
        int s = (int)r.x;
        float l = lrelu(a_src2[s] + adst + up2(r.w).x);
        if (l > m) {
            float sc = expf(m - l);
            denom *= sc;
#pragma unroll
            for (int f = 0; f < FD; ++f) acc[f] *= sc;
            m = l;
        }
        float ex = expf(l - m);
        denom += ex;
        GATHER_ACC(ex, &xh2h[(size_t)s * FP]);
    }
    float mo = __shfl_xor(m, 1);
    float dno = __shfl_xor(denom, 1);
    float M = fmaxf(m, mo);
    float ssf = expf(m - M), sof = expf(mo - M);
    denom = denom * ssf + dno * sof;
#pragma unroll
    for (int f = 0; f < FD; ++f) acc[f] = acc[f] * ssf + __shfl_xor(acc[f], 1) * sof;
    if (p) return;
    float inv = 1.0f / (denom + 1e-16f);
    float h2[FD];
#pragma unroll
    for (int f = 0; f < FD; ++f) h2[f] = elu(acc[f] * inv + sb2[f]);
    float o[OUTD];
#pragma unroll
    for (int k = 0; k < OUTD; ++k) o[k] = sD2b[k];
    for (int j = 0; j < 10; ++j) {
        float hid = sD1b[j];
#pragma unroll
        for (int f = 0; f < FD; ++f) hid += h2[f] * sD1w[f * 10 + j];
        hid = fmaxf(hid, 0.0f);
#pragma unroll
        for (int k = 0; k < OUTD; ++k) o[k] += hid * sD2w[j * OUTD + k];
    }
#pragma unroll
    for (int k = 0; k < OUTD; ++k) out[n * OUTD + k] = o[k];
}

extern "C" void kernel_launch(void* const* d_in, const int* in_sizes, int n_in,
                              void* d_out, int out_size, void* d_ws, size_t ws_size,
                              hipStream_t stream) {
    const float* x     = (const float*)d_in[0];
    const int*   ei    = (const int*)d_in[1];
    const float* eattr = (const float*)d_in[2];
    const float* W1    = (const float*)d_in[3];
    const float* as1   = (const float*)d_in[4];
    const float* ad1   = (const float*)d_in[5];
    const float* We1   = (const float*)d_in[6];
    const float* ae1   = (const float*)d_in[7];
    const float* b1    = (const float*)d_in[8];
    const float* W2    = (const float*)d_in[9];
    const float* as2   = (const float*)d_in[10];
    const float* ad2   = (const float*)d_in[11];
    const float* We2   = (const float*)d_in[12];
    const float* ae2   = (const float*)d_in[13];
    const float* b2    = (const float*)d_in[14];
    const float* D1w   = (const float*)d_in[15];
    const float* D1b   = (const float*)d_in[16];
    const float* D2w   = (const float*)d_in[17];
    const float* D2b   = (const float*)d_in[18];
    float* out = (float*)d_out;

    float* w = (float*)d_ws;
    size_t o = 0;
    // ---- zero-init region: only deg ----
    int*   deg = (int*)(w + o); o += NN;
    size_t zero_bytes = o * sizeof(float);
    // ---- rest (fully overwritten each call) ----
    int*   rank    = (int*)(w + o); o += EEg;
    int*   partial = (int*)(w + o); o += NN;
    int*   bsum    = (int*)(w + o); o += 256;
    int*   boff    = (int*)(w + o); o += 256;
    int*   row_off = (int*)(w + o); o += NN + 4;
    float* csr     = w + o; o += (size_t)EEg * 4;            // 16B records
    float* ve1     = w + o; o += 32;
    float* ve2     = w + o; o += 8;
    float* a_e1s   = w + o; o += (size_t)NN * H1D;
    float* a_e2s   = w + o; o += NN;
    float* a_src1  = w + o; o += (size_t)NN * H1D;
    float* a_dst1  = w + o; o += (size_t)NN * H1D;
    __half* xh1h   = (__half*)(w + o); o += (size_t)NN * H1D * FP / 2;
    float* h1      = w + o; o += (size_t)NN * H1D * FD;
    __half* xh2h   = (__half*)(w + o); o += (size_t)NN * FP / 2;
    float* a_src2  = w + o; o += NN;
    float* a_dst2  = w + o; o += NN;

    hipMemsetAsync(d_ws, 0, zero_bytes, stream);

    const int B = 256;
    auto cdiv = [](long a, long b) { return (int)((a + b - 1) / b); };
    const int NB = cdiv(NN, 256);

    k_deg<<<cdiv(EEg, B), B, 0, stream>>>(ei, deg, rank);
    k_ve<<<1, 64, 0, stream>>>(We1, ae1, We2, ae2, ve1, ve2);
    k_scanA<<<NB, 256, 0, stream>>>(deg, partial, bsum);
    k_scanB<<<1, 256, 0, stream>>>(bsum, boff, NB);
    k_scanC<<<NB, 256, 0, stream>>>(partial, boff, row_off);
    k_scatter<<<cdiv(EEg, B), B, 0, stream>>>(ei, eattr, ve1, ve2, row_off, rank,
                                              (uint4*)csr);
    k_mean_self<<<cdiv(NN, B), B, 0, stream>>>(row_off, (const uint4*)csr, a_e1s, a_e2s);
    k_xh1attn1<<<cdiv((long)NN * H1D, B), B, 0, stream>>>(x, W1, as1, ad1, xh1h, a_src1,
                                                          a_dst1);
    k_conv1<<<NN * 8 / 64, 64, 0, stream>>>(row_off, (const uint4*)csr, a_src1, a_dst1,
                                            a_e1s, xh1h, b1, h1);
    k_xh2attn2<<<cdiv(NN, B), B, 0, stream>>>(h1, W2, as2, ad2, xh2h, a_src2, a_dst2);
    k_conv2dec<<<cdiv((long)NN * 2, 64), 64, 0, stream>>>(row_off, (const uint4*)csr,
                                                          a_src2, a_dst2, a_e2s, xh2h, b2,
                                                          D1w, D1b, D2w, D2b, out);
}